// Round 6
// baseline (32.287 us; speedup 1.0000x reference)
//
#include <hip/hip_runtime.h>
#include <hip/hip_bf16.h>

typedef float f32x4 __attribute__((ext_vector_type(4)));

#define E_DIM 1024   // embed dim (output cols)
#define F_DIM 4096   // ffn dim
#define ROWS  16384  // B*S
#define NCG   64     // column groups (16 cols each)
#define NRG   16     // row groups (1024 rows each)

// Fully fused, no grid sync: block (cg, rg) computes o[16 cols of cg]
// (redundantly across the 16 rg-replicas; w_out slice is same-XCD L2-resident
// because replicas differ by bid multiples of 64 == 0 mod 8 XCDs), then
// streams its 1024-row x 64B column stripe with nontemporal stores.
// q = analytic 4-qubit circuit expvals; x/w1 are a dead path (RZ on |0> is a
// global phase) -> 64 MiB of input never read.
__global__ __launch_bounds__(256) void qff_fused(
    const float* __restrict__ w2,      // (4096, 4) row-major
    const float* __restrict__ wout,    // (1024, 4096) row-major
    const float* __restrict__ params,  // (4,)
    float* __restrict__ out)           // (16384, 1024)
{
    __shared__ float h[F_DIM];
    __shared__ float o_l[16];

    const int t = threadIdx.x;
    const int wave = t >> 6;
    const int lane = t & 63;
    const int cg = blockIdx.x & (NCG - 1);   // column group: cols [16cg, 16cg+16)
    const int rg = blockIdx.x >> 6;          // row group:   rows [1024rg, 1024rg+1024)

    // ---- phase 1: h = relu(w2 @ q) ----
    const float c0 = cosf(params[0]);
    const float c1 = cosf(params[1]);
    const float c2 = cosf(params[2]);
    const float c3 = cosf(params[3]);
    const float q0 = c1 * c2 * c3;
    const float q1 = c0 * c1;
    const float q2 = q1 * c2;
    const float q3 = q2 * c3;

    const f32x4* w2v = reinterpret_cast<const f32x4*>(w2);
    for (int g = t; g < F_DIM; g += 256) {
        f32x4 w = w2v[g];
        float v = w.x * q0 + w.y * q1 + w.z * q2 + w.w * q3;
        h[g] = v > 0.0f ? v : 0.0f;
    }
    __syncthreads();

    // ---- phase 2: o[i] = w_out[16cg+i, :] . h  for i in [0,16), 4 per wave ----
    const int e0 = cg * 16;
    const f32x4* h4 = reinterpret_cast<const f32x4*>(h);
    for (int i = wave; i < 16; i += 4) {
        const f32x4* wrow = reinterpret_cast<const f32x4*>(wout + (size_t)(e0 + i) * F_DIM);
        float s = 0.0f;
#pragma unroll
        for (int j = 0; j < F_DIM / 4 / 64; ++j) {   // 16 iterations
            f32x4 a = wrow[lane + j * 64];
            f32x4 b = h4[lane + j * 64];
            s += a.x * b.x + a.y * b.y + a.z * b.z + a.w * b.w;
        }
#pragma unroll
        for (int off = 32; off > 0; off >>= 1) s += __shfl_down(s, off);
        if (lane == 0) o_l[i] = s;
    }
    __syncthreads();

    // ---- phase 3: stream the stripe ----
    // thread owns float4-quad (t&3) of the 16 cols, rows r = rbase + k*64 + (t>>2).
    // Each 4-lane group writes one full 64B line -> no write amplification.
    const f32x4 v = reinterpret_cast<const f32x4*>(o_l)[t & 3];
    const int q4 = cg * 4 + (t & 3);               // float4 column index in [0,256)
    const int r0 = rg * 1024 + (t >> 2);
    f32x4* out4 = reinterpret_cast<f32x4*>(out);
#pragma unroll
    for (int k = 0; k < 16; ++k) {
        const int r = r0 + k * 64;
        __builtin_nontemporal_store(v, &out4[(size_t)r * (E_DIM / 4) + q4]);
    }
}

extern "C" void kernel_launch(void* const* d_in, const int* in_sizes, int n_in,
                              void* d_out, int out_size, void* d_ws, size_t ws_size,
                              hipStream_t stream) {
    // inputs (setup_inputs order): x, w1, w2, w_out, params — x/w1 never read.
    const float* w2     = (const float*)d_in[2];
    const float* w_out  = (const float*)d_in[3];
    const float* params = (const float*)d_in[4];
    float* out = (float*)d_out;

    qff_fused<<<NCG * NRG, 256, 0, stream>>>(w2, w_out, params, out);
}